// Round 6
// baseline (283.087 us; speedup 1.0000x reference)
//
#include <hip/hip_runtime.h>
#include <math.h>

#define B_ 128
#define G_ 16
#define A_ 8732
#define C_ 21
#define THR_ 0.5f
#define NEG_POS_ 3
#define VAR0_ 0.1f
#define VAR1_ 0.2f

#define BA_    (B_ * A_)             // 1,117,696
#define NGRPB_ (A_ / 4)              // 2183 4-anchor groups per batch (exact)
#define MBLKX_ ((A_ + 255) / 256)    // 35
#define LBLKX_ ((NGRPB_ + 255) / 256) // 9

struct Accum { float loss_loc; float loss_cls; int done; int pad; };

// ---------------------------------------------------------------------------
// K0: zero wsGT (2048 u64) + npos (128) + acc — contiguous region.
// ---------------------------------------------------------------------------
#define ZERO_U32_ (2048 * 2 + 128 + 4)
__global__ __launch_bounds__(256) void k_zero(unsigned int* z) {
    for (int i = threadIdx.x; i < ZERO_U32_; i += 256) z[i] = 0u;
}

// ---------------------------------------------------------------------------
// K1: matching, full grid. grid=(35,128), 1 anchor/thread.
// Per-anchor best (ov,gi) -> packed u64 ovgi[]. Per-GT best via wave-shuffle
// max + device atomicMax on packed (iou_bits<<32 | ~a)  (max iou, min a).
// ---------------------------------------------------------------------------
__global__ __launch_bounds__(256) void k_match(
    const float* __restrict__ tboxes,   // B,G,4 (point form)
    const float* __restrict__ anchors,  // A,4 (center form)
    unsigned long long* __restrict__ ovgi,  // B*A: ov_bits<<32 | gi
    unsigned long long* __restrict__ wsGT)  // B*G: iou_bits<<32 | ~a
{
    const int b    = blockIdx.y;
    const int tid  = threadIdx.x;
    const int a    = blockIdx.x * 256 + tid;
    const int lane = tid & 63;

    __shared__ float s_box[G_ * 4];
    if (tid < G_ * 4) s_box[tid] = tboxes[b * G_ * 4 + tid];
    __syncthreads();

    float bx0[G_], by0[G_], bx1[G_], by1[G_], bar[G_];
    #pragma unroll
    for (int g = 0; g < G_; ++g) {
        bx0[g] = s_box[g * 4 + 0];
        by0[g] = s_box[g * 4 + 1];
        bx1[g] = s_box[g * 4 + 2];
        by1[g] = s_box[g * 4 + 3];
        bar[g] = (bx1[g] - bx0[g]) * (by1[g] - by0[g]);
    }

    const bool valid = (a < A_);
    const int  aa    = valid ? a : (A_ - 1);
    float4 an = ((const float4*)anchors)[aa];
    float ax0 = an.x - an.z * 0.5f, ay0 = an.y - an.w * 0.5f;
    float ax1 = an.x + an.z * 0.5f, ay1 = an.y + an.w * 0.5f;
    float area_b = (ax1 - ax0) * (ay1 - ay0);   // mirror reference arithmetic

    float bov = -1.f; int bg = 0;
    #pragma unroll
    for (int g = 0; g < G_; ++g) {
        float tlx = fmaxf(bx0[g], ax0);
        float tly = fmaxf(by0[g], ay0);
        float brx = fminf(bx1[g], ax1);
        float bry = fminf(by1[g], ay1);
        float wdt = fmaxf(brx - tlx, 0.f);
        float hgt = fmaxf(bry - tly, 0.f);
        float inter = wdt * hgt;
        float iou = inter / (bar[g] + area_b - inter);   // IEEE div, bit-exact vs ref
        if (iou > bov) { bov = iou; bg = g; }            // first g wins on ties

        unsigned long long pk = valid
            ? ((unsigned long long)__float_as_uint(iou) << 32) |
              (unsigned)(~(unsigned)a)                    // max iou, min a on ties
            : 0ull;
        #pragma unroll
        for (int off = 32; off > 0; off >>= 1) {
            unsigned long long o = __shfl_down(pk, off);
            if (o > pk) pk = o;
        }
        if (lane == 0)
            atomicMax(&wsGT[b * G_ + g], pk);
    }

    if (valid)
        ovgi[(size_t)b * A_ + a] =
            ((unsigned long long)__float_as_uint(bov) << 32) | (unsigned)bg;
}

// ---------------------------------------------------------------------------
// K2: per-anchor loss. grid=(9,128), 4 anchors/thread, no LDS staging of conf.
// Forced matches applied inline via the 16 winner indices from wsGT.
// num_pos accumulated per batch; loss partials to device accumulator.
// ---------------------------------------------------------------------------
__global__ __launch_bounds__(256) void k_loss(
    const float* __restrict__ pred_off,   // B,A,4
    const float* __restrict__ pred_conf,  // B,A,C
    const float* __restrict__ tboxes,     // B,G,4
    const int*   __restrict__ tlabels,    // B,G
    const float* __restrict__ anchors,    // A,4
    const unsigned long long* __restrict__ ovgi,
    const unsigned long long* __restrict__ wsGT,
    float*       __restrict__ aux,        // flat BA
    int*         __restrict__ npos,       // B (pre-zeroed)
    Accum*                    acc)
{
    const int b    = blockIdx.y;
    const int tid  = threadIdx.x;
    const int gid  = blockIdx.x * 256 + tid;   // 4-anchor group within batch
    const int lane = tid & 63;
    const int w    = tid >> 6;

    __shared__ int    s_win[G_];
    __shared__ int    s_lab[G_];
    __shared__ float4 s_bx[G_];
    __shared__ float  s_lloc[4];
    __shared__ float  s_pnll[4];
    __shared__ int    s_cnt[4];

    if (tid < G_) {
        unsigned long long wv = wsGT[b * G_ + tid];
        s_win[tid] = (int)(~(unsigned)(wv & 0xffffffffull));
        s_lab[tid] = tlabels[b * G_ + tid];
        s_bx[tid]  = ((const float4*)tboxes)[b * G_ + tid];
    }
    __syncthreads();

    float lloc = 0.f, pnll = 0.f;
    int   cnt  = 0;

    if (gid < NGRPB_) {
        const float4* cp = (const float4*)pred_conf + ((size_t)b * NGRPB_ + gid) * 21;
        float xx[84];
        #pragma unroll
        for (int k = 0; k < 21; ++k) {
            float4 v = cp[k];
            xx[4 * k + 0] = v.x; xx[4 * k + 1] = v.y;
            xx[4 * k + 2] = v.z; xx[4 * k + 3] = v.w;
        }
        const ulonglong2* op = (const ulonglong2*)(ovgi + (size_t)b * A_) + gid * 2;
        ulonglong2 o01 = op[0];
        ulonglong2 o23 = op[1];
        unsigned long long ovp[4] = { o01.x, o01.y, o23.x, o23.y };
        float auxv[4];

        #pragma unroll
        for (int jj = 0; jj < 4; ++jj) {
            const int base = 21 * jj;
            const int a    = 4 * gid + jj;
            float ov = __uint_as_float((unsigned)(ovp[jj] >> 32));
            int   gi = (int)(ovp[jj] & 0xffull);
            #pragma unroll
            for (int g = 0; g < G_; ++g) {        // ascending g, last write wins
                if (s_win[g] == a) { ov = 1.0f; gi = g; }
            }
            int conf = (ov < THR_) ? 0 : (s_lab[gi] + 1);

            float m = xx[base];
            #pragma unroll
            for (int c = 1; c < C_; ++c) m = fmaxf(m, xx[base + c]);
            float s = 0.f;
            #pragma unroll
            for (int c = 0; c < C_; ++c) s += __expf(xx[base + c] - m);
            float lse = m + __logf(s);

            float xc = xx[base];
            #pragma unroll
            for (int c = 1; c < C_; ++c) xc = (conf == c) ? xx[base + c] : xc;
            float nll = lse - xc;
            bool pos = conf > 0;
            auxv[jj] = pos ? 0.f : nll;

            if (pos) {
                cnt++;
                pnll += nll;
                float4 an = ((const float4*)anchors)[a];
                float4 bx = s_bx[gi];
                float gcx = (bx.x + bx.z) * 0.5f, gcy = (bx.y + bx.w) * 0.5f;
                float gw = bx.z - bx.x, gh = bx.w - bx.y;
                float l0 = (gcx - an.x) / (an.z * VAR0_);
                float l1 = (gcy - an.y) / (an.w * VAR0_);
                float l2 = logf(gw / an.z) / VAR1_;
                float l3 = logf(gh / an.w) / VAR1_;
                float4 p = ((const float4*)pred_off)[(size_t)b * A_ + a];
                float d, ad;
                d = p.x - l0; ad = fabsf(d); lloc += (ad < 1.f) ? 0.5f * d * d : ad - 0.5f;
                d = p.y - l1; ad = fabsf(d); lloc += (ad < 1.f) ? 0.5f * d * d : ad - 0.5f;
                d = p.z - l2; ad = fabsf(d); lloc += (ad < 1.f) ? 0.5f * d * d : ad - 0.5f;
                d = p.w - l3; ad = fabsf(d); lloc += (ad < 1.f) ? 0.5f * d * d : ad - 0.5f;
            }
        }
        ((float4*)(aux + (size_t)b * A_))[gid] =
            make_float4(auxv[0], auxv[1], auxv[2], auxv[3]);
    }

    #pragma unroll
    for (int off = 32; off > 0; off >>= 1) {
        lloc += __shfl_down(lloc, off);
        pnll += __shfl_down(pnll, off);
        cnt  += __shfl_down(cnt, off);
    }
    if (lane == 0) { s_lloc[w] = lloc; s_pnll[w] = pnll; s_cnt[w] = cnt; }
    __syncthreads();
    if (tid == 0) {
        float L = s_lloc[0] + s_lloc[1] + s_lloc[2] + s_lloc[3];
        float P = s_pnll[0] + s_pnll[1] + s_pnll[2] + s_pnll[3];
        int   Ct = s_cnt[0] + s_cnt[1] + s_cnt[2] + s_cnt[3];
        if (L != 0.f) atomicAdd(&acc->loss_loc, L);
        if (P != 0.f) atomicAdd(&acc->loss_cls, P);
        if (Ct)       atomicAdd(&npos[b], Ct);
    }
}

// ---------------------------------------------------------------------------
// K3: per-batch hard-negative mining + in-kernel finalize (last block).
// ---------------------------------------------------------------------------
#define NPT_ 35   // ceil(8732/256)
__global__ __launch_bounds__(256) void k_select(
    const float* __restrict__ aux,
    const int*   __restrict__ num_pos,
    Accum*                    acc,
    float*       __restrict__ out)
{
    const int b    = blockIdx.x;
    const int tid  = threadIdx.x;
    const int lane = tid & 63;
    const int w    = tid >> 6;           // 0..3

    __shared__ int   s_c[2][4];
    __shared__ int   s_cf[4];
    __shared__ float s_sf[4];
    __shared__ int   s_last;

    unsigned u[NPT_];
    #pragma unroll
    for (int j = 0; j < NPT_; ++j) {
        int a = tid + j * 256;
        u[j] = (a < A_) ? __float_as_uint(aux[(size_t)b * A_ + a]) : 0u;
    }

    const int K = min(NEG_POS_ * num_pos[b], A_ - 1);

    unsigned lo = 0u, hi = 0x7f800000u;
    int it = 0;
    while (lo < hi) {
        unsigned mid = (lo + hi) >> 1;
        int c = 0;
        #pragma unroll
        for (int j = 0; j < NPT_; ++j) c += (u[j] > mid);
        #pragma unroll
        for (int off = 32; off > 0; off >>= 1) c += __shfl_down(c, off);
        if (lane == 0) s_c[it & 1][w] = c;
        __syncthreads();
        int total = s_c[it & 1][0] + s_c[it & 1][1] + s_c[it & 1][2] + s_c[it & 1][3];
        if (total >= K) lo = mid + 1; else hi = mid;
        ++it;
    }
    // lo == bit pattern of T = K-th largest value

    int c = 0; float sm = 0.f;
    #pragma unroll
    for (int j = 0; j < NPT_; ++j) {
        if (u[j] > lo) { c++; sm += __uint_as_float(u[j]); }
    }
    #pragma unroll
    for (int off = 32; off > 0; off >>= 1) {
        c  += __shfl_down(c, off);
        sm += __shfl_down(sm, off);
    }
    if (lane == 0) { s_cf[w] = c; s_sf[w] = sm; }
    __syncthreads();
    if (tid == 0) {
        int   ct = s_cf[0] + s_cf[1] + s_cf[2] + s_cf[3];
        float st = s_sf[0] + s_sf[1] + s_sf[2] + s_sf[3];
        float T = __uint_as_float(lo);
        atomicAdd(&acc->loss_cls, st + (float)(K - ct) * T);
        __threadfence();
        int prev = atomicAdd(&acc->done, 1);
        s_last = (prev == B_ - 1) ? 1 : 0;
    }
    __syncthreads();

    if (s_last) {
        int n = (tid < B_) ? num_pos[tid] : 0;
        #pragma unroll
        for (int off = 32; off > 0; off >>= 1) n += __shfl_down(n, off);
        if (lane == 0) s_cf[w] = n;
        __syncthreads();
        if (tid == 0) {
            float nt = (float)(s_cf[0] + s_cf[1]);
            float L  = atomicAdd(&acc->loss_loc, 0.f);
            float Cc = atomicAdd(&acc->loss_cls, 0.f);
            out[0] = L / nt;
            out[1] = Cc / nt;
        }
    }
}

// ---------------------------------------------------------------------------
extern "C" void kernel_launch(void* const* d_in, const int* in_sizes, int n_in,
                              void* d_out, int out_size, void* d_ws, size_t ws_size,
                              hipStream_t stream) {
    const float* pred_off  = (const float*)d_in[0];  // B,A,4
    const float* pred_conf = (const float*)d_in[1];  // B,A,C
    const float* tboxes    = (const float*)d_in[2];  // B,G,4
    const int*   tlabels   = (const int*)  d_in[3];  // B,G
    const float* anchors   = (const float*)d_in[4];  // A,4
    float* out = (float*)d_out;

    char* ws = (char*)d_ws;
    unsigned long long* ovgi = (unsigned long long*)ws;
    ws += (size_t)BA_ * sizeof(unsigned long long);
    float* aux_ws = (float*)ws;
    ws += (size_t)BA_ * sizeof(float);
    // contiguous zero region: wsGT | npos | acc
    unsigned long long* wsGT = (unsigned long long*)ws;
    ws += (size_t)B_ * G_ * sizeof(unsigned long long);
    int* npos_ws = (int*)ws;
    ws += (size_t)B_ * sizeof(int);
    Accum* acc = (Accum*)ws;

    k_zero<<<1, 256, 0, stream>>>((unsigned int*)wsGT);
    {
        dim3 g(MBLKX_, B_);
        k_match<<<g, 256, 0, stream>>>(tboxes, anchors, ovgi, wsGT);
    }
    {
        dim3 g(LBLKX_, B_);
        k_loss<<<g, 256, 0, stream>>>(pred_off, pred_conf, tboxes, tlabels, anchors,
                                      ovgi, wsGT, aux_ws, npos_ws, acc);
    }
    k_select<<<B_, 256, 0, stream>>>(aux_ws, npos_ws, acc, out);
}

// Round 7
// 244.055 us; speedup vs baseline: 1.1599x; 1.1599x over previous
//
#include <hip/hip_runtime.h>
#include <math.h>

#define B_ 128
#define G_ 16
#define A_ 8732
#define C_ 21
#define THR_ 0.5f
#define NEG_POS_ 3
#define VAR0_ 0.1f
#define VAR1_ 0.2f

#define BA_    (B_ * A_)              // 1,117,696
#define NGRPB_ (A_ / 4)               // 2183 4-anchor groups per batch (exact)
#define MBLKX_ ((A_ + 255) / 256)     // 35
#define LBLKX_ ((NGRPB_ + 255) / 256) // 9

struct Accum { float loss_loc; float loss_cls; int done; int pad; };

// ---------------------------------------------------------------------------
// K1a: per-anchor best match. grid=(35,128), 1 anchor/thread.
// NO shuffles, NO atomics — 16 IoUs + one packed store.
// Block (0,0) also zeroes npos + acc (consumed only by later launches).
// ---------------------------------------------------------------------------
__global__ __launch_bounds__(256) void k_match_a(
    const float* __restrict__ tboxes,   // B,G,4 (point form)
    const float* __restrict__ anchors,  // A,4 (center form)
    unsigned long long* __restrict__ ovgi,  // B*A: ov_bits<<32 | gi
    int*         __restrict__ npos,     // B
    Accum*                    acc)
{
    const int b   = blockIdx.y;
    const int tid = threadIdx.x;
    const int a   = blockIdx.x * 256 + tid;

    if (blockIdx.x == 0 && b == 0) {
        if (tid < B_) npos[tid] = 0;
        if (tid == 0) { acc->loss_loc = 0.f; acc->loss_cls = 0.f; acc->done = 0; }
    }

    __shared__ float s_box[G_ * 4];
    if (tid < G_ * 4) s_box[tid] = tboxes[b * G_ * 4 + tid];
    __syncthreads();

    if (a >= A_) return;

    float4 an = ((const float4*)anchors)[a];
    float ax0 = an.x - an.z * 0.5f, ay0 = an.y - an.w * 0.5f;
    float ax1 = an.x + an.z * 0.5f, ay1 = an.y + an.w * 0.5f;
    float area_b = (ax1 - ax0) * (ay1 - ay0);   // mirror reference arithmetic

    float bov = -1.f; int bg = 0;
    #pragma unroll
    for (int g = 0; g < G_; ++g) {
        float bx0 = s_box[g * 4 + 0], by0 = s_box[g * 4 + 1];
        float bx1 = s_box[g * 4 + 2], by1 = s_box[g * 4 + 3];
        float bar = (bx1 - bx0) * (by1 - by0);
        float tlx = fmaxf(bx0, ax0);
        float tly = fmaxf(by0, ay0);
        float brx = fminf(bx1, ax1);
        float bry = fminf(by1, ay1);
        float wdt = fmaxf(brx - tlx, 0.f);
        float hgt = fmaxf(bry - tly, 0.f);
        float inter = wdt * hgt;
        float iou = inter / (bar + area_b - inter);  // IEEE div, bit-exact vs ref
        if (iou > bov) { bov = iou; bg = g; }        // first g wins on ties
    }

    ovgi[(size_t)b * A_ + a] =
        ((unsigned long long)__float_as_uint(bov) << 32) | (unsigned)bg;
}

// ---------------------------------------------------------------------------
// K1b: per-GT best anchor. One WAVE per (b,g) pair: 512 blocks x 4 waves.
// Lane-strided scan over A, register packed-u64 max, single shuffle reduce,
// direct store — no atomics.
// ---------------------------------------------------------------------------
__global__ __launch_bounds__(256) void k_match_g(
    const float* __restrict__ tboxes,   // B,G,4
    const float* __restrict__ anchors,  // A,4
    unsigned long long* __restrict__ wsGT)  // B*G: iou_bits<<32 | ~a
{
    const int tid  = threadIdx.x;
    const int lane = tid & 63;
    const int pair = blockIdx.x * 4 + (tid >> 6);   // (b,g) index, 0..2047
    const int b    = pair >> 4;
    const int g    = pair & 15;

    // wave-uniform GT box (broadcast load)
    float4 bx = ((const float4*)tboxes)[b * G_ + g];
    float bx0 = bx.x, by0 = bx.y, bx1 = bx.z, by1 = bx.w;
    float bar = (bx1 - bx0) * (by1 - by0);

    unsigned long long best = 0ull;
    for (int a = lane; a < A_; a += 64) {
        float4 an = ((const float4*)anchors)[a];
        float ax0 = an.x - an.z * 0.5f, ay0 = an.y - an.w * 0.5f;
        float ax1 = an.x + an.z * 0.5f, ay1 = an.y + an.w * 0.5f;
        float area_b = (ax1 - ax0) * (ay1 - ay0);
        float tlx = fmaxf(bx0, ax0);
        float tly = fmaxf(by0, ay0);
        float brx = fminf(bx1, ax1);
        float bry = fminf(by1, ay1);
        float wdt = fmaxf(brx - tlx, 0.f);
        float hgt = fmaxf(bry - tly, 0.f);
        float inter = wdt * hgt;
        float iou = inter / (bar + area_b - inter);
        unsigned long long pk =
            ((unsigned long long)__float_as_uint(iou) << 32) |
            (unsigned)(~(unsigned)a);               // max iou, min a on ties
        if (pk > best) best = pk;
    }
    #pragma unroll
    for (int off = 32; off > 0; off >>= 1) {
        unsigned long long o = __shfl_down(best, off);
        if (o > best) best = o;
    }
    if (lane == 0) wsGT[pair] = best;
}

// ---------------------------------------------------------------------------
// K2: per-anchor loss. grid=(9,128), 4 anchors/thread, register-resident
// logits. Forced matches applied inline via the 16 winner indices from wsGT.
// ---------------------------------------------------------------------------
__global__ __launch_bounds__(256) void k_loss(
    const float* __restrict__ pred_off,   // B,A,4
    const float* __restrict__ pred_conf,  // B,A,C
    const float* __restrict__ tboxes,     // B,G,4
    const int*   __restrict__ tlabels,    // B,G
    const float* __restrict__ anchors,    // A,4
    const unsigned long long* __restrict__ ovgi,
    const unsigned long long* __restrict__ wsGT,
    float*       __restrict__ aux,        // flat BA
    int*         __restrict__ npos,       // B (pre-zeroed)
    Accum*                    acc)
{
    const int b    = blockIdx.y;
    const int tid  = threadIdx.x;
    const int gid  = blockIdx.x * 256 + tid;   // 4-anchor group within batch
    const int lane = tid & 63;
    const int w    = tid >> 6;

    __shared__ int    s_win[G_];
    __shared__ int    s_lab[G_];
    __shared__ float4 s_bx[G_];
    __shared__ float  s_lloc[4];
    __shared__ float  s_pnll[4];
    __shared__ int    s_cnt[4];

    if (tid < G_) {
        unsigned long long wv = wsGT[b * G_ + tid];
        s_win[tid] = (int)(~(unsigned)(wv & 0xffffffffull));
        s_lab[tid] = tlabels[b * G_ + tid];
        s_bx[tid]  = ((const float4*)tboxes)[b * G_ + tid];
    }
    __syncthreads();

    float lloc = 0.f, pnll = 0.f;
    int   cnt  = 0;

    if (gid < NGRPB_) {
        const float4* cp = (const float4*)pred_conf + ((size_t)b * NGRPB_ + gid) * 21;
        float xx[84];
        #pragma unroll
        for (int k = 0; k < 21; ++k) {
            float4 v = cp[k];
            xx[4 * k + 0] = v.x; xx[4 * k + 1] = v.y;
            xx[4 * k + 2] = v.z; xx[4 * k + 3] = v.w;
        }
        const ulonglong2* op = (const ulonglong2*)(ovgi + (size_t)b * A_) + gid * 2;
        ulonglong2 o01 = op[0];
        ulonglong2 o23 = op[1];
        unsigned long long ovp[4] = { o01.x, o01.y, o23.x, o23.y };
        float auxv[4];

        #pragma unroll
        for (int jj = 0; jj < 4; ++jj) {
            const int base = 21 * jj;
            const int a    = 4 * gid + jj;
            float ov = __uint_as_float((unsigned)(ovp[jj] >> 32));
            int   gi = (int)(ovp[jj] & 0xffull);
            #pragma unroll
            for (int g = 0; g < G_; ++g) {        // ascending g, last write wins
                if (s_win[g] == a) { ov = 1.0f; gi = g; }
            }
            int conf = (ov < THR_) ? 0 : (s_lab[gi] + 1);

            float m = xx[base];
            #pragma unroll
            for (int c = 1; c < C_; ++c) m = fmaxf(m, xx[base + c]);
            float s = 0.f;
            #pragma unroll
            for (int c = 0; c < C_; ++c) s += __expf(xx[base + c] - m);
            float lse = m + __logf(s);

            float xc = xx[base];
            #pragma unroll
            for (int c = 1; c < C_; ++c) xc = (conf == c) ? xx[base + c] : xc;
            float nll = lse - xc;
            bool pos = conf > 0;
            auxv[jj] = pos ? 0.f : nll;

            if (pos) {
                cnt++;
                pnll += nll;
                float4 an = ((const float4*)anchors)[a];
                float4 bxv = s_bx[gi];
                float gcx = (bxv.x + bxv.z) * 0.5f, gcy = (bxv.y + bxv.w) * 0.5f;
                float gw = bxv.z - bxv.x, gh = bxv.w - bxv.y;
                float l0 = (gcx - an.x) / (an.z * VAR0_);
                float l1 = (gcy - an.y) / (an.w * VAR0_);
                float l2 = logf(gw / an.z) / VAR1_;
                float l3 = logf(gh / an.w) / VAR1_;
                float4 p = ((const float4*)pred_off)[(size_t)b * A_ + a];
                float d, ad;
                d = p.x - l0; ad = fabsf(d); lloc += (ad < 1.f) ? 0.5f * d * d : ad - 0.5f;
                d = p.y - l1; ad = fabsf(d); lloc += (ad < 1.f) ? 0.5f * d * d : ad - 0.5f;
                d = p.z - l2; ad = fabsf(d); lloc += (ad < 1.f) ? 0.5f * d * d : ad - 0.5f;
                d = p.w - l3; ad = fabsf(d); lloc += (ad < 1.f) ? 0.5f * d * d : ad - 0.5f;
            }
        }
        ((float4*)(aux + (size_t)b * A_))[gid] =
            make_float4(auxv[0], auxv[1], auxv[2], auxv[3]);
    }

    #pragma unroll
    for (int off = 32; off > 0; off >>= 1) {
        lloc += __shfl_down(lloc, off);
        pnll += __shfl_down(pnll, off);
        cnt  += __shfl_down(cnt, off);
    }
    if (lane == 0) { s_lloc[w] = lloc; s_pnll[w] = pnll; s_cnt[w] = cnt; }
    __syncthreads();
    if (tid == 0) {
        float L = s_lloc[0] + s_lloc[1] + s_lloc[2] + s_lloc[3];
        float P = s_pnll[0] + s_pnll[1] + s_pnll[2] + s_pnll[3];
        int   Ct = s_cnt[0] + s_cnt[1] + s_cnt[2] + s_cnt[3];
        if (L != 0.f) atomicAdd(&acc->loss_loc, L);
        if (P != 0.f) atomicAdd(&acc->loss_cls, P);
        if (Ct)       atomicAdd(&npos[b], Ct);
    }
}

// ---------------------------------------------------------------------------
// K3: per-batch hard-negative mining + in-kernel finalize (last block).
// ---------------------------------------------------------------------------
#define NPT_ 35   // ceil(8732/256)
__global__ __launch_bounds__(256) void k_select(
    const float* __restrict__ aux,
    const int*   __restrict__ num_pos,
    Accum*                    acc,
    float*       __restrict__ out)
{
    const int b    = blockIdx.x;
    const int tid  = threadIdx.x;
    const int lane = tid & 63;
    const int w    = tid >> 6;           // 0..3

    __shared__ int   s_c[2][4];
    __shared__ int   s_cf[4];
    __shared__ float s_sf[4];
    __shared__ int   s_last;

    unsigned u[NPT_];
    #pragma unroll
    for (int j = 0; j < NPT_; ++j) {
        int a = tid + j * 256;
        u[j] = (a < A_) ? __float_as_uint(aux[(size_t)b * A_ + a]) : 0u;
    }

    const int K = min(NEG_POS_ * num_pos[b], A_ - 1);

    unsigned lo = 0u, hi = 0x7f800000u;
    int it = 0;
    while (lo < hi) {
        unsigned mid = (lo + hi) >> 1;
        int c = 0;
        #pragma unroll
        for (int j = 0; j < NPT_; ++j) c += (u[j] > mid);
        #pragma unroll
        for (int off = 32; off > 0; off >>= 1) c += __shfl_down(c, off);
        if (lane == 0) s_c[it & 1][w] = c;
        __syncthreads();
        int total = s_c[it & 1][0] + s_c[it & 1][1] + s_c[it & 1][2] + s_c[it & 1][3];
        if (total >= K) lo = mid + 1; else hi = mid;
        ++it;
    }
    // lo == bit pattern of T = K-th largest value

    int c = 0; float sm = 0.f;
    #pragma unroll
    for (int j = 0; j < NPT_; ++j) {
        if (u[j] > lo) { c++; sm += __uint_as_float(u[j]); }
    }
    #pragma unroll
    for (int off = 32; off > 0; off >>= 1) {
        c  += __shfl_down(c, off);
        sm += __shfl_down(sm, off);
    }
    if (lane == 0) { s_cf[w] = c; s_sf[w] = sm; }
    __syncthreads();
    if (tid == 0) {
        int   ct = s_cf[0] + s_cf[1] + s_cf[2] + s_cf[3];
        float st = s_sf[0] + s_sf[1] + s_sf[2] + s_sf[3];
        float T = __uint_as_float(lo);
        atomicAdd(&acc->loss_cls, st + (float)(K - ct) * T);
        __threadfence();
        int prev = atomicAdd(&acc->done, 1);
        s_last = (prev == B_ - 1) ? 1 : 0;
    }
    __syncthreads();

    if (s_last) {
        int n = (tid < B_) ? num_pos[tid] : 0;
        #pragma unroll
        for (int off = 32; off > 0; off >>= 1) n += __shfl_down(n, off);
        if (lane == 0) s_cf[w] = n;
        __syncthreads();
        if (tid == 0) {
            float nt = (float)(s_cf[0] + s_cf[1]);
            float L  = atomicAdd(&acc->loss_loc, 0.f);
            float Cc = atomicAdd(&acc->loss_cls, 0.f);
            out[0] = L / nt;
            out[1] = Cc / nt;
        }
    }
}

// ---------------------------------------------------------------------------
extern "C" void kernel_launch(void* const* d_in, const int* in_sizes, int n_in,
                              void* d_out, int out_size, void* d_ws, size_t ws_size,
                              hipStream_t stream) {
    const float* pred_off  = (const float*)d_in[0];  // B,A,4
    const float* pred_conf = (const float*)d_in[1];  // B,A,C
    const float* tboxes    = (const float*)d_in[2];  // B,G,4
    const int*   tlabels   = (const int*)  d_in[3];  // B,G
    const float* anchors   = (const float*)d_in[4];  // A,4
    float* out = (float*)d_out;

    char* ws = (char*)d_ws;
    unsigned long long* ovgi = (unsigned long long*)ws;
    ws += (size_t)BA_ * sizeof(unsigned long long);
    float* aux_ws = (float*)ws;
    ws += (size_t)BA_ * sizeof(float);
    unsigned long long* wsGT = (unsigned long long*)ws;
    ws += (size_t)B_ * G_ * sizeof(unsigned long long);
    int* npos_ws = (int*)ws;
    ws += (size_t)B_ * sizeof(int);
    Accum* acc = (Accum*)ws;

    {
        dim3 g(MBLKX_, B_);
        k_match_a<<<g, 256, 0, stream>>>(tboxes, anchors, ovgi, npos_ws, acc);
    }
    k_match_g<<<(B_ * G_) / 4, 256, 0, stream>>>(tboxes, anchors, wsGT);
    {
        dim3 g(LBLKX_, B_);
        k_loss<<<g, 256, 0, stream>>>(pred_off, pred_conf, tboxes, tlabels, anchors,
                                      ovgi, wsGT, aux_ws, npos_ws, acc);
    }
    k_select<<<B_, 256, 0, stream>>>(aux_ws, npos_ws, acc, out);
}

// Round 8
// 243.221 us; speedup vs baseline: 1.1639x; 1.0034x over previous
//
#include <hip/hip_runtime.h>
#include <math.h>

#define B_ 128
#define G_ 16
#define A_ 8732
#define C_ 21
#define THR_ 0.5f
#define NEG_POS_ 3
#define VAR0_ 0.1f
#define VAR1_ 0.2f

#define BA_    (B_ * A_)              // 1,117,696
#define NGRPB_ (A_ / 4)               // 2183 4-anchor groups per batch (exact)
#define MBLKX_ ((A_ + 255) / 256)     // 35
#define LBLKX_ ((NGRPB_ + 255) / 256) // 9

struct Accum { float loss_loc; float loss_cls; int done; int pad; };

// ---------------------------------------------------------------------------
// K1a: per-anchor best match. grid=(35,128), 1 anchor/thread.
// NO shuffles, NO atomics — 16 IoUs + one packed store.
// Block (0,0) also zeroes npos + acc (consumed only by later launches).
// ---------------------------------------------------------------------------
__global__ __launch_bounds__(256) void k_match_a(
    const float* __restrict__ tboxes,   // B,G,4 (point form)
    const float* __restrict__ anchors,  // A,4 (center form)
    unsigned long long* __restrict__ ovgi,  // B*A: ov_bits<<32 | gi
    int*         __restrict__ npos,     // B
    Accum*                    acc)
{
    const int b   = blockIdx.y;
    const int tid = threadIdx.x;
    const int a   = blockIdx.x * 256 + tid;

    if (blockIdx.x == 0 && b == 0) {
        if (tid < B_) npos[tid] = 0;
        if (tid == 0) { acc->loss_loc = 0.f; acc->loss_cls = 0.f; acc->done = 0; }
    }

    __shared__ float s_box[G_ * 4];
    if (tid < G_ * 4) s_box[tid] = tboxes[b * G_ * 4 + tid];
    __syncthreads();

    if (a >= A_) return;

    float4 an = ((const float4*)anchors)[a];
    float ax0 = an.x - an.z * 0.5f, ay0 = an.y - an.w * 0.5f;
    float ax1 = an.x + an.z * 0.5f, ay1 = an.y + an.w * 0.5f;
    float area_b = (ax1 - ax0) * (ay1 - ay0);   // mirror reference arithmetic

    float bov = -1.f; int bg = 0;
    #pragma unroll
    for (int g = 0; g < G_; ++g) {
        float bx0 = s_box[g * 4 + 0], by0 = s_box[g * 4 + 1];
        float bx1 = s_box[g * 4 + 2], by1 = s_box[g * 4 + 3];
        float bar = (bx1 - bx0) * (by1 - by0);
        float tlx = fmaxf(bx0, ax0);
        float tly = fmaxf(by0, ay0);
        float brx = fminf(bx1, ax1);
        float bry = fminf(by1, ay1);
        float wdt = fmaxf(brx - tlx, 0.f);
        float hgt = fmaxf(bry - tly, 0.f);
        float inter = wdt * hgt;
        float iou = inter / (bar + area_b - inter);  // IEEE div, bit-exact vs ref
        if (iou > bov) { bov = iou; bg = g; }        // first g wins on ties
    }

    ovgi[(size_t)b * A_ + a] =
        ((unsigned long long)__float_as_uint(bov) << 32) | (unsigned)bg;
}

// ---------------------------------------------------------------------------
// K1b: per-GT best anchor. One WAVE per (b,g) pair: 512 blocks x 4 waves.
// Lane-strided scan over A, register packed-u64 max, single shuffle reduce,
// direct store — no atomics.
// ---------------------------------------------------------------------------
__global__ __launch_bounds__(256) void k_match_g(
    const float* __restrict__ tboxes,   // B,G,4
    const float* __restrict__ anchors,  // A,4
    unsigned long long* __restrict__ wsGT)  // B*G: iou_bits<<32 | ~a
{
    const int tid  = threadIdx.x;
    const int lane = tid & 63;
    const int pair = blockIdx.x * 4 + (tid >> 6);   // (b,g) index, 0..2047
    const int b    = pair >> 4;
    const int g    = pair & 15;

    // wave-uniform GT box (broadcast load)
    float4 bx = ((const float4*)tboxes)[b * G_ + g];
    float bx0 = bx.x, by0 = bx.y, bx1 = bx.z, by1 = bx.w;
    float bar = (bx1 - bx0) * (by1 - by0);

    unsigned long long best = 0ull;
    for (int a = lane; a < A_; a += 64) {
        float4 an = ((const float4*)anchors)[a];
        float ax0 = an.x - an.z * 0.5f, ay0 = an.y - an.w * 0.5f;
        float ax1 = an.x + an.z * 0.5f, ay1 = an.y + an.w * 0.5f;
        float area_b = (ax1 - ax0) * (ay1 - ay0);
        float tlx = fmaxf(bx0, ax0);
        float tly = fmaxf(by0, ay0);
        float brx = fminf(bx1, ax1);
        float bry = fminf(by1, ay1);
        float wdt = fmaxf(brx - tlx, 0.f);
        float hgt = fmaxf(bry - tly, 0.f);
        float inter = wdt * hgt;
        float iou = inter / (bar + area_b - inter);
        unsigned long long pk =
            ((unsigned long long)__float_as_uint(iou) << 32) |
            (unsigned)(~(unsigned)a);               // max iou, min a on ties
        if (pk > best) best = pk;
    }
    #pragma unroll
    for (int off = 32; off > 0; off >>= 1) {
        unsigned long long o = __shfl_down(best, off);
        if (o > best) best = o;
    }
    if (lane == 0) wsGT[pair] = best;
}

// ---------------------------------------------------------------------------
// K2: per-anchor loss. grid=(9,128), 4 anchors/thread.
// __launch_bounds__(256, 1): allow up to ~512 VGPR so xx[84] is truly
// register-resident (default bounds spilled it to scratch -> 57 µs latency
// wall at VGPR_Count=60).
// ---------------------------------------------------------------------------
__global__ __launch_bounds__(256, 1) void k_loss(
    const float* __restrict__ pred_off,   // B,A,4
    const float* __restrict__ pred_conf,  // B,A,C
    const float* __restrict__ tboxes,     // B,G,4
    const int*   __restrict__ tlabels,    // B,G
    const float* __restrict__ anchors,    // A,4
    const unsigned long long* __restrict__ ovgi,
    const unsigned long long* __restrict__ wsGT,
    float*       __restrict__ aux,        // flat BA
    int*         __restrict__ npos,       // B (pre-zeroed)
    Accum*                    acc)
{
    const int b    = blockIdx.y;
    const int tid  = threadIdx.x;
    const int gid  = blockIdx.x * 256 + tid;   // 4-anchor group within batch
    const int lane = tid & 63;
    const int w    = tid >> 6;

    __shared__ int    s_win[G_];
    __shared__ int    s_lab[G_];
    __shared__ float4 s_bx[G_];
    __shared__ float  s_lloc[4];
    __shared__ float  s_pnll[4];
    __shared__ int    s_cnt[4];

    if (tid < G_) {
        unsigned long long wv = wsGT[b * G_ + tid];
        s_win[tid] = (int)(~(unsigned)(wv & 0xffffffffull));
        s_lab[tid] = tlabels[b * G_ + tid];
        s_bx[tid]  = ((const float4*)tboxes)[b * G_ + tid];
    }
    __syncthreads();

    float lloc = 0.f, pnll = 0.f;
    int   cnt  = 0;

    if (gid < NGRPB_) {
        const float4* cp = (const float4*)pred_conf + ((size_t)b * NGRPB_ + gid) * 21;
        float xx[84];
        #pragma unroll
        for (int k = 0; k < 21; ++k) {
            float4 v = cp[k];
            xx[4 * k + 0] = v.x; xx[4 * k + 1] = v.y;
            xx[4 * k + 2] = v.z; xx[4 * k + 3] = v.w;
        }
        const ulonglong2* op = (const ulonglong2*)(ovgi + (size_t)b * A_) + gid * 2;
        ulonglong2 o01 = op[0];
        ulonglong2 o23 = op[1];
        unsigned long long ovp[4] = { o01.x, o01.y, o23.x, o23.y };
        float auxv[4];

        #pragma unroll
        for (int jj = 0; jj < 4; ++jj) {
            const int base = 21 * jj;
            const int a    = 4 * gid + jj;
            float ov = __uint_as_float((unsigned)(ovp[jj] >> 32));
            int   gi = (int)(ovp[jj] & 0xffull);
            #pragma unroll
            for (int g = 0; g < G_; ++g) {        // ascending g, last write wins
                if (s_win[g] == a) { ov = 1.0f; gi = g; }
            }
            int conf = (ov < THR_) ? 0 : (s_lab[gi] + 1);

            float m = xx[base];
            #pragma unroll
            for (int c = 1; c < C_; ++c) m = fmaxf(m, xx[base + c]);
            float s = 0.f;
            #pragma unroll
            for (int c = 0; c < C_; ++c) s += __expf(xx[base + c] - m);
            float lse = m + __logf(s);

            float xc = xx[base];
            #pragma unroll
            for (int c = 1; c < C_; ++c) xc = (conf == c) ? xx[base + c] : xc;
            float nll = lse - xc;
            bool pos = conf > 0;
            auxv[jj] = pos ? 0.f : nll;

            if (pos) {
                cnt++;
                pnll += nll;
                float4 an = ((const float4*)anchors)[a];
                float4 bxv = s_bx[gi];
                float gcx = (bxv.x + bxv.z) * 0.5f, gcy = (bxv.y + bxv.w) * 0.5f;
                float gw = bxv.z - bxv.x, gh = bxv.w - bxv.y;
                float l0 = (gcx - an.x) / (an.z * VAR0_);
                float l1 = (gcy - an.y) / (an.w * VAR0_);
                float l2 = logf(gw / an.z) / VAR1_;
                float l3 = logf(gh / an.w) / VAR1_;
                float4 p = ((const float4*)pred_off)[(size_t)b * A_ + a];
                float d, ad;
                d = p.x - l0; ad = fabsf(d); lloc += (ad < 1.f) ? 0.5f * d * d : ad - 0.5f;
                d = p.y - l1; ad = fabsf(d); lloc += (ad < 1.f) ? 0.5f * d * d : ad - 0.5f;
                d = p.z - l2; ad = fabsf(d); lloc += (ad < 1.f) ? 0.5f * d * d : ad - 0.5f;
                d = p.w - l3; ad = fabsf(d); lloc += (ad < 1.f) ? 0.5f * d * d : ad - 0.5f;
            }
        }
        ((float4*)(aux + (size_t)b * A_))[gid] =
            make_float4(auxv[0], auxv[1], auxv[2], auxv[3]);
    }

    #pragma unroll
    for (int off = 32; off > 0; off >>= 1) {
        lloc += __shfl_down(lloc, off);
        pnll += __shfl_down(pnll, off);
        cnt  += __shfl_down(cnt, off);
    }
    if (lane == 0) { s_lloc[w] = lloc; s_pnll[w] = pnll; s_cnt[w] = cnt; }
    __syncthreads();
    if (tid == 0) {
        float L = s_lloc[0] + s_lloc[1] + s_lloc[2] + s_lloc[3];
        float P = s_pnll[0] + s_pnll[1] + s_pnll[2] + s_pnll[3];
        int   Ct = s_cnt[0] + s_cnt[1] + s_cnt[2] + s_cnt[3];
        if (L != 0.f) atomicAdd(&acc->loss_loc, L);
        if (P != 0.f) atomicAdd(&acc->loss_cls, P);
        if (Ct)       atomicAdd(&npos[b], Ct);
    }
}

// ---------------------------------------------------------------------------
// K3: per-batch hard-negative mining + in-kernel finalize (last block).
// ---------------------------------------------------------------------------
#define NPT_ 35   // ceil(8732/256)
__global__ __launch_bounds__(256) void k_select(
    const float* __restrict__ aux,
    const int*   __restrict__ num_pos,
    Accum*                    acc,
    float*       __restrict__ out)
{
    const int b    = blockIdx.x;
    const int tid  = threadIdx.x;
    const int lane = tid & 63;
    const int w    = tid >> 6;           // 0..3

    __shared__ int   s_c[2][4];
    __shared__ int   s_cf[4];
    __shared__ float s_sf[4];
    __shared__ int   s_last;

    unsigned u[NPT_];
    #pragma unroll
    for (int j = 0; j < NPT_; ++j) {
        int a = tid + j * 256;
        u[j] = (a < A_) ? __float_as_uint(aux[(size_t)b * A_ + a]) : 0u;
    }

    const int K = min(NEG_POS_ * num_pos[b], A_ - 1);

    unsigned lo = 0u, hi = 0x7f800000u;
    int it = 0;
    while (lo < hi) {
        unsigned mid = (lo + hi) >> 1;
        int c = 0;
        #pragma unroll
        for (int j = 0; j < NPT_; ++j) c += (u[j] > mid);
        #pragma unroll
        for (int off = 32; off > 0; off >>= 1) c += __shfl_down(c, off);
        if (lane == 0) s_c[it & 1][w] = c;
        __syncthreads();
        int total = s_c[it & 1][0] + s_c[it & 1][1] + s_c[it & 1][2] + s_c[it & 1][3];
        if (total >= K) lo = mid + 1; else hi = mid;
        ++it;
    }
    // lo == bit pattern of T = K-th largest value

    int c = 0; float sm = 0.f;
    #pragma unroll
    for (int j = 0; j < NPT_; ++j) {
        if (u[j] > lo) { c++; sm += __uint_as_float(u[j]); }
    }
    #pragma unroll
    for (int off = 32; off > 0; off >>= 1) {
        c  += __shfl_down(c, off);
        sm += __shfl_down(sm, off);
    }
    if (lane == 0) { s_cf[w] = c; s_sf[w] = sm; }
    __syncthreads();
    if (tid == 0) {
        int   ct = s_cf[0] + s_cf[1] + s_cf[2] + s_cf[3];
        float st = s_sf[0] + s_sf[1] + s_sf[2] + s_sf[3];
        float T = __uint_as_float(lo);
        atomicAdd(&acc->loss_cls, st + (float)(K - ct) * T);
        __threadfence();
        int prev = atomicAdd(&acc->done, 1);
        s_last = (prev == B_ - 1) ? 1 : 0;
    }
    __syncthreads();

    if (s_last) {
        int n = (tid < B_) ? num_pos[tid] : 0;
        #pragma unroll
        for (int off = 32; off > 0; off >>= 1) n += __shfl_down(n, off);
        if (lane == 0) s_cf[w] = n;
        __syncthreads();
        if (tid == 0) {
            float nt = (float)(s_cf[0] + s_cf[1]);
            float L  = atomicAdd(&acc->loss_loc, 0.f);
            float Cc = atomicAdd(&acc->loss_cls, 0.f);
            out[0] = L / nt;
            out[1] = Cc / nt;
        }
    }
}

// ---------------------------------------------------------------------------
extern "C" void kernel_launch(void* const* d_in, const int* in_sizes, int n_in,
                              void* d_out, int out_size, void* d_ws, size_t ws_size,
                              hipStream_t stream) {
    const float* pred_off  = (const float*)d_in[0];  // B,A,4
    const float* pred_conf = (const float*)d_in[1];  // B,A,C
    const float* tboxes    = (const float*)d_in[2];  // B,G,4
    const int*   tlabels   = (const int*)  d_in[3];  // B,G
    const float* anchors   = (const float*)d_in[4];  // A,4
    float* out = (float*)d_out;

    char* ws = (char*)d_ws;
    unsigned long long* ovgi = (unsigned long long*)ws;
    ws += (size_t)BA_ * sizeof(unsigned long long);
    float* aux_ws = (float*)ws;
    ws += (size_t)BA_ * sizeof(float);
    unsigned long long* wsGT = (unsigned long long*)ws;
    ws += (size_t)B_ * G_ * sizeof(unsigned long long);
    int* npos_ws = (int*)ws;
    ws += (size_t)B_ * sizeof(int);
    Accum* acc = (Accum*)ws;

    {
        dim3 g(MBLKX_, B_);
        k_match_a<<<g, 256, 0, stream>>>(tboxes, anchors, ovgi, npos_ws, acc);
    }
    k_match_g<<<(B_ * G_) / 4, 256, 0, stream>>>(tboxes, anchors, wsGT);
    {
        dim3 g(LBLKX_, B_);
        k_loss<<<g, 256, 0, stream>>>(pred_off, pred_conf, tboxes, tlabels, anchors,
                                      ovgi, wsGT, aux_ws, npos_ws, acc);
    }
    k_select<<<B_, 256, 0, stream>>>(aux_ws, npos_ws, acc, out);
}